// Round 14
// baseline (163.819 us; speedup 1.0000x reference)
//
#include <hip/hip_runtime.h>
#include <hip/hip_fp16.h>

typedef _Float16 f16;
typedef __attribute__((ext_vector_type(8))) _Float16 f16x8;
typedef __attribute__((ext_vector_type(4))) _Float16 f16x4;
typedef __attribute__((ext_vector_type(2))) __fp16 fp16x2;
typedef __attribute__((ext_vector_type(4))) float f32x4;
typedef __attribute__((ext_vector_type(16))) float f32x16;

#define DM 1024
#define NH 16
#define DH 64
#define TT 2048
#define LOG2E 1.4426950408889634f
#define QSCALE 0.18033688f   /* 0.125 * log2(e) */

#define SB0 __builtin_amdgcn_sched_barrier(0)
#define LGKM0 asm volatile("s_waitcnt lgkmcnt(0)" ::: "memory")

// ---------------- fragment-order bias table generator (only remaining pre-pass) ----------------
// FBf unit c (f16x8): half=c&1, lane=(c>>1)&63, kvt=(c>>7)&63, qt=c>>13.
// elem e: i = qt*32+(lane&31), j = kvt*32 + 16*half + 8*(lane>>5) + e ; val = |i-j|/30
__global__ __launch_bounds__(256) void fbgen(f16* __restrict__ FBf) {
  int c = blockIdx.x * 256 + threadIdx.x;   // grid 2048 -> 524288 units
  int half = c & 1, lane = (c >> 1) & 63, kvt = (c >> 7) & 63, qt = c >> 13;
  int qi = qt * 32 + (lane & 31);
  int jb = kvt * 32 + 16 * half + 8 * (lane >> 5);
  f16x8 v;
#pragma unroll
  for (int e = 0; e < 8; e++) {
    int d = qi - (jb + e); d = (d < 0) ? -d : d;
    v[e] = (f16)(d / 30);
  }
  reinterpret_cast<f16x8*>(FBf)[c] = v;
}

// ---------------- RNE f32x8 -> f16x8 convert (identical math to the old cvt_all) ----------------
__device__ __forceinline__ f16x8 cvt8rne(float4 a, float4 b, float s) {
  f16x8 v;
  v[0] = (f16)(a.x * s); v[1] = (f16)(a.y * s); v[2] = (f16)(a.z * s); v[3] = (f16)(a.w * s);
  v[4] = (f16)(b.x * s); v[5] = (f16)(b.y * s); v[6] = (f16)(b.z * s); v[7] = (f16)(b.w * s);
  return v;
}

// ---------------- GEMM mainloop: reg-staged async split + raw barriers, fused f32->f16 convert ----------------
// 128x128 tile, BK=32. A operand: f32 (A32) or f16; B operand: f32 (B32, scaled) or f16.
// LOADR one K-step ahead -> regs; WRITE converts (if f32) + ds_writes just before the
// barrier; lgkmcnt(0)-only waits; vmcnt NEVER drained.
template<bool A32, bool B32>
__device__ __forceinline__ void gemm_mainloop_t(const void* Ap, const void* Wp,
                                                int bm, int bn, float bscale,
                                                f16 (*As)[4096], f16 (*Bs)[4096],
                                                f32x4 (&acc)[4][4]) {
  int t = threadIdx.x;
  int w = t >> 6;
  int lane = t & 63, lr = lane & 15, g = lane >> 4;
  int wr = w >> 1, wc = w & 1;
  int scol = ((t & 3) ^ ((t >> 3) & 3)) * 8;
  int szg = ((lr >> 1) & 3) << 4;

  const float* a32 = (const float*)Ap + (size_t)(bm + (t >> 2)) * DM + scol;
  const f16*   a16 = (const f16*)Ap + (size_t)(bm + (t >> 2)) * DM + scol;
  const float* b32 = (const float*)Wp + (size_t)(bn + (t >> 2)) * DM + scol;
  const f16*   b16 = (const f16*)Wp + (size_t)(bn + (t >> 2)) * DM + scol;

  float4 rAf[4], rBf[4];
  f16x8 rA[2], rB[2];

  auto LOADR = [&](int kt) {
    if constexpr (A32) {
      rAf[0] = *reinterpret_cast<const float4*>(a32 + kt);
      rAf[1] = *reinterpret_cast<const float4*>(a32 + kt + 4);
      rAf[2] = *reinterpret_cast<const float4*>(a32 + (size_t)64 * DM + kt);
      rAf[3] = *reinterpret_cast<const float4*>(a32 + (size_t)64 * DM + kt + 4);
    } else {
      rA[0] = *reinterpret_cast<const f16x8*>(a16 + kt);
      rA[1] = *reinterpret_cast<const f16x8*>(a16 + (size_t)64 * DM + kt);
    }
    if constexpr (B32) {
      rBf[0] = *reinterpret_cast<const float4*>(b32 + kt);
      rBf[1] = *reinterpret_cast<const float4*>(b32 + kt + 4);
      rBf[2] = *reinterpret_cast<const float4*>(b32 + (size_t)64 * DM + kt);
      rBf[3] = *reinterpret_cast<const float4*>(b32 + (size_t)64 * DM + kt + 4);
    } else {
      rB[0] = *reinterpret_cast<const f16x8*>(b16 + kt);
      rB[1] = *reinterpret_cast<const f16x8*>(b16 + (size_t)64 * DM + kt);
    }
  };
  auto WRITE = [&](int bufi) {
    char* Ab = (char*)As[bufi];
    char* Bb = (char*)Bs[bufi];
    f16x8 uA0 = A32 ? cvt8rne(rAf[0], rAf[1], 1.0f) : rA[0];
    f16x8 uA1 = A32 ? cvt8rne(rAf[2], rAf[3], 1.0f) : rA[1];
    f16x8 uB0 = B32 ? cvt8rne(rBf[0], rBf[1], bscale) : rB[0];
    f16x8 uB1 = B32 ? cvt8rne(rBf[2], rBf[3], bscale) : rB[1];
    *reinterpret_cast<f16x8*>(Ab + t * 16) = uA0;
    *reinterpret_cast<f16x8*>(Ab + 4096 + t * 16) = uA1;
    *reinterpret_cast<f16x8*>(Bb + t * 16) = uB0;
    *reinterpret_cast<f16x8*>(Bb + 4096 + t * 16) = uB1;
  };
  auto CMPG = [&](int bufi) {
    const char* Ab = (const char*)As[bufi];
    const char* Bb = (const char*)Bs[bufi];
    f16x8 af[4], bf[4];
#pragma unroll
    for (int mi = 0; mi < 4; mi++) {
      int row = wr * 64 + mi * 16 + lr;
      af[mi] = *reinterpret_cast<const f16x8*>(Ab + row * 64 + ((g << 4) ^ szg));
    }
#pragma unroll
    for (int ni = 0; ni < 4; ni++) {
      int row = wc * 64 + ni * 16 + lr;
      bf[ni] = *reinterpret_cast<const f16x8*>(Bb + row * 64 + ((g << 4) ^ szg));
    }
    __builtin_amdgcn_s_setprio(1);
#pragma unroll
    for (int mi = 0; mi < 4; mi++)
#pragma unroll
      for (int ni = 0; ni < 4; ni++)
        acc[mi][ni] = __builtin_amdgcn_mfma_f32_16x16x32_f16(af[mi], bf[ni], acc[mi][ni], 0, 0, 0);
    __builtin_amdgcn_s_setprio(0);
  };

  LOADR(0);
  WRITE(0);
  LOADR(32);
  LGKM0;
  __builtin_amdgcn_s_barrier();
  SB0;

#pragma unroll 1
  for (int tp = 0; tp < 16; tp++) {
    int s0 = 2 * tp;
    CMPG(0);
    WRITE(1);
    if (s0 + 2 < 32) LOADR((s0 + 2) * 32);
    LGKM0;
    __builtin_amdgcn_s_barrier();
    SB0;
    CMPG(1);
    if (s0 + 2 < 32) {
      WRITE(0);
      if (s0 + 3 < 32) LOADR((s0 + 3) * 32);
      LGKM0;
      __builtin_amdgcn_s_barrier();
      SB0;
    }
  }
}

// ---------------- fused QKV projection (reads f32 x/context/weights directly) ----------------
__global__ __launch_bounds__(256) void qkv_gemm(const float* __restrict__ x, const float* __restrict__ cx,
                                                const float* __restrict__ wq, const float* __restrict__ wk,
                                                const float* __restrict__ wv,
                                                f16* __restrict__ Qo, f16* __restrict__ Ko,
                                                f16* __restrict__ Vt) {
  __shared__ f16 As[2][4096];
  __shared__ f16 Bs[2][4096];
  int gid = blockIdx.x >> 8;
  int bid = blockIdx.x & 255;
  int bm = (bid >> 3) * 128, bn = (bid & 7) * 128;
  const float* A = (gid == 0) ? x : cx;
  const float* W = (gid == 0) ? wq : ((gid == 1) ? wk : wv);
  float bscale = (gid == 0) ? QSCALE : 1.0f;
  f32x4 acc[4][4] = {};
  gemm_mainloop_t<true, true>(A, W, bm, bn, bscale, As, Bs, acc);

  int t = threadIdx.x, w = t >> 6, lane = t & 63, lr = lane & 15, g = lane >> 4;
  int wr = w >> 1, wc = w & 1;
  if (gid < 2) {
    f16* out = (gid == 0) ? Qo : Ko;
#pragma unroll
    for (int mi = 0; mi < 4; mi++) {
      int m0 = bm + wr * 64 + mi * 16 + 4 * g;
      int b = m0 >> 11, i0 = m0 & 2047;
#pragma unroll
      for (int ni = 0; ni < 4; ni++) {
        int n = bn + wc * 64 + ni * 16 + lr;
        int h = n >> 6, d = n & 63;
        size_t base = (((size_t)(b * NH + h)) * TT + i0) * DH + d;
#pragma unroll
        for (int r = 0; r < 4; r++)
          out[base + (size_t)r * DH] = (f16)acc[mi][ni][r];
      }
    }
  } else {
#pragma unroll
    for (int mi = 0; mi < 4; mi++) {
      int m0 = bm + wr * 64 + mi * 16 + 4 * g;
      int b = m0 >> 11, j0 = m0 & 2047;
#pragma unroll
      for (int ni = 0; ni < 4; ni++) {
        int n = bn + wc * 64 + ni * 16 + lr;
        int h = n >> 6, d = n & 63;
        f16x4 pk = { (f16)acc[mi][ni][0], (f16)acc[mi][ni][1],
                     (f16)acc[mi][ni][2], (f16)acc[mi][ni][3] };
        *reinterpret_cast<f16x4*>(&Vt[(((size_t)(b * NH + h)) * DH + d) * TT + j0]) = pk;
      }
    }
  }
}

// ---------------- output projection (A = f16 Ob, B = f32 Wo converted on the fly) ----------------
__global__ __launch_bounds__(256) void out_gemm(const f16* __restrict__ Ob, const float* __restrict__ wo,
                                                const float* __restrict__ bo, float* __restrict__ Y) {
  __shared__ f16 As[2][4096];
  __shared__ f16 Bs[2][4096];
  int bid = blockIdx.x;
  int bm = (bid >> 3) * 128, bn = (bid & 7) * 128;
  f32x4 acc[4][4] = {};
  gemm_mainloop_t<false, true>(Ob, wo, bm, bn, 1.0f, As, Bs, acc);
  int t = threadIdx.x, w = t >> 6, lane = t & 63, lr = lane & 15, g = lane >> 4;
  int wr = w >> 1, wc = w & 1;
#pragma unroll
  for (int mi = 0; mi < 4; mi++) {
    int m0 = bm + wr * 64 + mi * 16 + 4 * g;
#pragma unroll
    for (int ni = 0; ni < 4; ni++) {
      int n = bn + wc * 64 + ni * 16 + lr;
      float bias = bo[n];
#pragma unroll
      for (int r = 0; r < 4; r++)
        Y[(size_t)(m0 + r) * DM + n] = acc[mi][ni][r] + bias;
    }
  }
}

// ---------------- flash attention: R10/R12 exact (4-wave, reg-staged, raw barriers) ----------------
struct FB4 { f16x8 a, b, c, d; };

__global__ __launch_bounds__(256, 2) void attn_kernel(const f16* __restrict__ Q, const f16* __restrict__ K,
                                                      const f16* __restrict__ V, const f16* __restrict__ FBf,
                                                      f16* __restrict__ O) {
  __shared__ f16 KV[2][8192];   // 16KB per buf: K @0, V^T @+8KB
  int o = blockIdx.x;
  int xcd = o & 7, idx = o >> 3;            // XCD-aware: 4 bh per XCD
  int bh = 4 * xcd + (idx >> 4), qblk = idx & 15;
  int h = bh & 15, b = bh >> 4;
  int tt = threadIdx.x, w = tt >> 6, lane = tt & 63;
  int col = lane & 31, hi = lane >> 5;
  int qi = qblk * 128 + w * 32 + col;

  const f16* qp = Q + ((size_t)bh * TT + qi) * DH + hi * 8;
  f16x8 qf[4];
#pragma unroll
  for (int s = 0; s < 4; s++) qf[s] = *reinterpret_cast<const f16x8*>(qp + 16 * s);

  const float nc2 = -exp2f(-(float)(h + 1)) * LOG2E;
  int qtp = qblk * 4 + w;
  const f16x8* fbp = reinterpret_cast<const f16x8*>(FBf) + ((size_t)qtp << 13) + (lane << 1);

  f32x4 rsv = { 0.f, 0.f, 0.f, 0.f };
  f32x16 oacc0 = {}, oacc1 = {};

  int rho0 = tt >> 3, G = tt & 7;
  int f0 = (rho0 & 7) ^ (3 * ((rho0 >> 4) & 1));
  int J0 = (rho0 & 19) | ((rho0 & 4) << 1) | ((rho0 & 8) >> 1);   // swap bits 2<->3
  const f16* kp0 = K + ((size_t)bh * TT + J0) * DH + (G ^ f0) * 8;
  const f16* kp1 = K + ((size_t)bh * TT + 32 + J0) * DH + (G ^ f0) * 8;
  const f16* vp0 = V + ((size_t)bh * DH + rho0) * TT + (G ^ f0) * 8;
  const f16* vp1 = V + ((size_t)bh * DH + 32 + rho0) * TT + (G ^ f0) * 8;

  f16x8 r0, r1, r2, r3;
  auto LOADR = [&](int kv0) {
    r0 = *reinterpret_cast<const f16x8*>(kp0 + (size_t)kv0 * DH);
    r1 = *reinterpret_cast<const f16x8*>(kp1 + (size_t)kv0 * DH);
    r2 = *reinterpret_cast<const f16x8*>(vp0 + kv0);
    r3 = *reinterpret_cast<const f16x8*>(vp1 + kv0);
  };
  auto WRITE = [&](int bufi) {
    char* base = (char*)KV[bufi];
    *reinterpret_cast<f16x8*>(base + tt * 16) = r0;
    *reinterpret_cast<f16x8*>(base + 4096 + tt * 16) = r1;
    *reinterpret_cast<f16x8*>(base + 8192 + tt * 16) = r2;
    *reinterpret_cast<f16x8*>(base + 12288 + tt * 16) = r3;
  };

  int fcol = (col & 7) ^ (3 * ((col >> 4) & 1));
  int kb0 = col * 128;
  int ksw[4];
#pragma unroll
  for (int s = 0; s < 4; s++) ksw[s] = ((2 * s + hi) ^ fcol) << 4;

  auto FBLOAD = [&](int t) {
    FB4 f;
    f.a = fbp[256 * t];
    f.b = fbp[256 * t + 1];
    f.c = fbp[256 * t + 128];
    f.d = fbp[256 * t + 129];
    return f;
  };

  auto CMP = [&](int bufi, const FB4& fb) {
    const char* Kb = (const char*)KV[bufi];
    f32x16 S0 = {}, S1 = {};
    __builtin_amdgcn_s_setprio(1);
#pragma unroll
    for (int s = 0; s < 4; s++) {
      f16x8 ka0 = *reinterpret_cast<const f16x8*>(Kb + kb0 + ksw[s]);
      f16x8 ka1 = *reinterpret_cast<const f16x8*>(Kb + 4096 + kb0 + ksw[s]);
      S0 = __builtin_amdgcn_mfma_f32_32x32x16_f16(ka0, qf[s], S0, 0, 0, 0);
      S1 = __builtin_amdgcn_mfma_f32_32x32x16_f16(ka1, qf[s], S1, 0, 0, 0);
    }
    __builtin_amdgcn_s_setprio(0);
    float p0[16], p1[16];
#pragma unroll
    for (int r = 0; r < 16; r++) {
      float fb0 = (float)((r < 8) ? fb.a[r] : fb.b[r - 8]);
      float fb1 = (float)((r < 8) ? fb.c[r] : fb.d[r - 8]);
      p0[r] = __builtin_amdgcn_exp2f(fmaf(fb0, nc2, S0[r]));
      p1[r] = __builtin_amdgcn_exp2f(fmaf(fb1, nc2, S1[r]));
    }
#pragma unroll
    for (int r = 0; r < 4; r++) {
      f32x4 pa = { p0[4 * r], p0[4 * r + 1], p0[4 * r + 2], p0[4 * r + 3] };
      f32x4 pc = { p1[4 * r], p1[4 * r + 1], p1[4 * r + 2], p1[4 * r + 3] };
      rsv += pa + pc;
    }
    f16x8 pb[4];
#pragma unroll
    for (int s2 = 0; s2 < 2; s2++) {
      union { f16x8 v; fp16x2 hh[4]; } u0, u1;
#pragma unroll
      for (int q2 = 0; q2 < 4; q2++) {
        u0.hh[q2] = __builtin_amdgcn_cvt_pkrtz(p0[8 * s2 + 2 * q2], p0[8 * s2 + 2 * q2 + 1]);
        u1.hh[q2] = __builtin_amdgcn_cvt_pkrtz(p1[8 * s2 + 2 * q2], p1[8 * s2 + 2 * q2 + 1]);
      }
      pb[s2] = u0.v; pb[2 + s2] = u1.v;
    }
    __builtin_amdgcn_s_setprio(1);
#pragma unroll
    for (int s2 = 0; s2 < 4; s2++) {
      f16x8 va0 = *reinterpret_cast<const f16x8*>(Kb + 8192 + kb0 + ksw[s2]);
      f16x8 va1 = *reinterpret_cast<const f16x8*>(Kb + 12288 + kb0 + ksw[s2]);
      oacc0 = __builtin_amdgcn_mfma_f32_32x32x16_f16(va0, pb[s2], oacc0, 0, 0, 0);
      oacc1 = __builtin_amdgcn_mfma_f32_32x32x16_f16(va1, pb[s2], oacc1, 0, 0, 0);
    }
    __builtin_amdgcn_s_setprio(0);
  };

  LOADR(0);
  WRITE(0);
  LOADR(64);
  FB4 fA = FBLOAD(0);
  FB4 fB = FBLOAD(1);
  LGKM0;
  __builtin_amdgcn_s_barrier();
  SB0;

#pragma unroll 1
  for (int tp = 0; tp < 16; tp++) {
    int t0 = 2 * tp;
    CMP(0, fA);
    WRITE(1);
    if (t0 + 2 < 32) { LOADR((t0 + 2) << 6); fA = FBLOAD(t0 + 2); }
    LGKM0;
    __builtin_amdgcn_s_barrier();
    SB0;
    CMP(1, fB);
    if (t0 + 2 < 32) {
      WRITE(0);
      if (t0 + 3 < 32) { LOADR((t0 + 3) << 6); fB = FBLOAD(t0 + 3); }
      LGKM0;
      __builtin_amdgcn_s_barrier();
      SB0;
    }
  }

  float lsum = (rsv[0] + rsv[1]) + (rsv[2] + rsv[3]);
  lsum += __shfl_xor(lsum, 32, 64);
  float inv = __builtin_amdgcn_rcpf(lsum);

  size_t ob = ((size_t)b * TT + qi) * DM + h * DH + 4 * hi;
  const f32x16* oa[2] = { &oacc0, &oacc1 };
#pragma unroll
  for (int db = 0; db < 2; db++)
#pragma unroll
    for (int a = 0; a < 4; a++) {
      f16x4 o4 = { (f16)((*oa[db])[4 * a] * inv),     (f16)((*oa[db])[4 * a + 1] * inv),
                   (f16)((*oa[db])[4 * a + 2] * inv), (f16)((*oa[db])[4 * a + 3] * inv) };
      *reinterpret_cast<f16x4*>(&O[ob + 32 * db + 8 * a]) = o4;
    }
}

extern "C" void kernel_launch(void* const* d_in, const int* in_sizes, int n_in,
                              void* d_out, int out_size, void* d_ws, size_t ws_size,
                              hipStream_t stream) {
  const float* x  = (const float*)d_in[0];
  const float* cx = (const float*)d_in[1];
  const float* Wq = (const float*)d_in[2];
  const float* Wk = (const float*)d_in[3];
  const float* Wv = (const float*)d_in[4];
  const float* Wo = (const float*)d_in[5];
  const float* bo = (const float*)d_in[6];
  float* Y = (float*)d_out;

  const size_t NTOK = (size_t)2 * TT;
  f16* p = (f16*)d_ws;
  f16* Qb  = p; p += NTOK * DM;
  f16* Kb  = p; p += NTOK * DM;
  f16* Vtb = p; p += NTOK * DM;
  f16* Ob  = p; p += NTOK * DM;
  f16* FBt = p;   // 8MB fragment-order bias table

  fbgen<<<2048, 256, 0, stream>>>(FBt);
  qkv_gemm<<<768, 256, 0, stream>>>(x, cx, Wq, Wk, Wv, Qb, Kb, Vtb);
  attn_kernel<<<512, 256, 0, stream>>>(Qb, Kb, Vtb, FBt, Ob);
  out_gemm<<<256, 256, 0, stream>>>(Ob, Wo, bo, Y);
}

// Round 15
// 124.358 us; speedup vs baseline: 1.3173x; 1.3173x over previous
//
#include <hip/hip_runtime.h>
#include <hip/hip_fp16.h>

typedef _Float16 f16;
typedef __attribute__((ext_vector_type(8))) _Float16 f16x8;
typedef __attribute__((ext_vector_type(4))) _Float16 f16x4;
typedef __attribute__((ext_vector_type(2))) __fp16 fp16x2;
typedef __attribute__((ext_vector_type(4))) float f32x4;
typedef __attribute__((ext_vector_type(16))) float f32x16;

#define DM 1024
#define NH 16
#define DH 64
#define TT 2048
#define LOG2E 1.4426950408889634f
#define QSCALE 0.18033688f   /* 0.125 * log2(e) */

#define SB0 __builtin_amdgcn_sched_barrier(0)
#define LGKM0 asm volatile("s_waitcnt lgkmcnt(0)" ::: "memory")

// ---------------- fused f32->f16 convert (6 tensors) + fragment-order bias table ----------------
// FBf unit c (f16x8): half=c&1, lane=(c>>1)&63, kvt=(c>>7)&63, qt=c>>13.
// elem e: i = qt*32+(lane&31), j = kvt*32 + 16*half + 8*(lane>>5) + e ; val = |i-j|/30
__global__ __launch_bounds__(256) void cvt_all(const float* __restrict__ x, const float* __restrict__ cx,
                                               const float* __restrict__ wq, const float* __restrict__ wk,
                                               const float* __restrict__ wv, const float* __restrict__ wo,
                                               f16* __restrict__ xb, f16* __restrict__ cb,
                                               f16* __restrict__ wqb, f16* __restrict__ wkb,
                                               f16* __restrict__ wvb, f16* __restrict__ wob,
                                               f16* __restrict__ FBf) {
  int idx = blockIdx.x * 256 + threadIdx.x;
  int stride = gridDim.x * 256;
  for (int i = idx; i < 3670016; i += stride) {
    if (i >= 3145728) {
      int c = i - 3145728;
      int half = c & 1, lane = (c >> 1) & 63, kvt = (c >> 7) & 63, qt = c >> 13;
      int qi = qt * 32 + (lane & 31);
      int jb = kvt * 32 + 16 * half + 8 * (lane >> 5);
      f16x8 v;
#pragma unroll
      for (int e = 0; e < 8; e++) {
        int d = qi - (jb + e); d = (d < 0) ? -d : d;
        v[e] = (f16)(d / 30);
      }
      reinterpret_cast<f16x8*>(FBf)[c] = v;
      continue;
    }
    const float* src; f16* dst; int off; float s = 1.0f;
    if (i < 2097152) {
      if (i < 1048576) { src = x; dst = xb; off = i; }
      else { src = cx; dst = cb; off = i - 1048576; }
    } else {
      int j = i - 2097152;
      int wsel = j >> 18;
      off = j & 262143;
      if (wsel == 0) { src = wq; dst = wqb; s = QSCALE; }
      else if (wsel == 1) { src = wk; dst = wkb; }
      else if (wsel == 2) { src = wv; dst = wvb; }
      else { src = wo; dst = wob; }
    }
    float4 v = reinterpret_cast<const float4*>(src)[off];
    f16x4 o = { (f16)(v.x * s), (f16)(v.y * s), (f16)(v.z * s), (f16)(v.w * s) };
    reinterpret_cast<f16x4*>(dst)[off] = o;
  }
}

// ---------------- shared GEMM mainloop: reg-staged async split + raw barriers (R12) ----------------
__device__ __forceinline__ void gemm_mainloop(const f16* __restrict__ A, const f16* __restrict__ W,
                                              int bm, int bn, f16 (*As)[4096], f16 (*Bs)[4096],
                                              f32x4 (&acc)[4][4]) {
  int t = threadIdx.x;
  int w = t >> 6;
  int lane = t & 63, lr = lane & 15, g = lane >> 4;
  int wr = w >> 1, wc = w & 1;
  int scol = ((t & 3) ^ ((t >> 3) & 3)) * 8;
  const f16* a0 = A + (size_t)(bm + (t >> 2)) * DM + scol;
  const f16* a1 = a0 + (size_t)64 * DM;
  const f16* b0 = W + (size_t)(bn + (t >> 2)) * DM + scol;
  const f16* b1 = b0 + (size_t)64 * DM;
  int szg = ((lr >> 1) & 3) << 4;

  f16x8 rA0, rA1, rB0, rB1;
  auto LOADR = [&](int kt) {
    rA0 = *reinterpret_cast<const f16x8*>(a0 + kt);
    rA1 = *reinterpret_cast<const f16x8*>(a1 + kt);
    rB0 = *reinterpret_cast<const f16x8*>(b0 + kt);
    rB1 = *reinterpret_cast<const f16x8*>(b1 + kt);
  };
  auto WRITE = [&](int bufi) {
    char* Ab = (char*)As[bufi];
    char* Bb = (char*)Bs[bufi];
    *reinterpret_cast<f16x8*>(Ab + t * 16) = rA0;
    *reinterpret_cast<f16x8*>(Ab + 4096 + t * 16) = rA1;
    *reinterpret_cast<f16x8*>(Bb + t * 16) = rB0;
    *reinterpret_cast<f16x8*>(Bb + 4096 + t * 16) = rB1;
  };
  auto CMPG = [&](int bufi) {
    const char* Ab = (const char*)As[bufi];
    const char* Bb = (const char*)Bs[bufi];
    f16x8 af[4], bf[4];
#pragma unroll
    for (int mi = 0; mi < 4; mi++) {
      int row = wr * 64 + mi * 16 + lr;
      af[mi] = *reinterpret_cast<const f16x8*>(Ab + row * 64 + ((g << 4) ^ szg));
    }
#pragma unroll
    for (int ni = 0; ni < 4; ni++) {
      int row = wc * 64 + ni * 16 + lr;
      bf[ni] = *reinterpret_cast<const f16x8*>(Bb + row * 64 + ((g << 4) ^ szg));
    }
    __builtin_amdgcn_s_setprio(1);
#pragma unroll
    for (int mi = 0; mi < 4; mi++)
#pragma unroll
      for (int ni = 0; ni < 4; ni++)
        acc[mi][ni] = __builtin_amdgcn_mfma_f32_16x16x32_f16(af[mi], bf[ni], acc[mi][ni], 0, 0, 0);
    __builtin_amdgcn_s_setprio(0);
  };

  LOADR(0);
  WRITE(0);
  LOADR(32);
  LGKM0;
  __builtin_amdgcn_s_barrier();
  SB0;

#pragma unroll 1
  for (int tp = 0; tp < 16; tp++) {
    int s0 = 2 * tp;
    CMPG(0);
    WRITE(1);
    if (s0 + 2 < 32) LOADR((s0 + 2) * 32);
    LGKM0;
    __builtin_amdgcn_s_barrier();
    SB0;
    CMPG(1);
    if (s0 + 2 < 32) {
      WRITE(0);
      if (s0 + 3 < 32) LOADR((s0 + 3) * 32);
      LGKM0;
      __builtin_amdgcn_s_barrier();
      SB0;
    }
  }
}

// ---------------- fused QKV projection (XCD-chunked tile mapping: 96 contiguous tiles/XCD) ----------------
__global__ __launch_bounds__(256) void qkv_gemm(const f16* __restrict__ xb, const f16* __restrict__ cb,
                                                const f16* __restrict__ wq, const f16* __restrict__ wk,
                                                const f16* __restrict__ wv,
                                                f16* __restrict__ Qo, f16* __restrict__ Ko,
                                                f16* __restrict__ Vt) {
  __shared__ f16 As[2][4096];
  __shared__ f16 Bs[2][4096];
  int o = blockIdx.x;
  int lin = (o & 7) * 96 + (o >> 3);   // each XCD owns a contiguous 96-tile chunk
  int gid = lin >> 8;
  int bid = lin & 255;
  int bm = (bid >> 3) * 128, bn = (bid & 7) * 128;
  const f16* A = (gid == 0) ? xb : cb;
  const f16* W = (gid == 0) ? wq : ((gid == 1) ? wk : wv);
  f32x4 acc[4][4] = {};
  gemm_mainloop(A, W, bm, bn, As, Bs, acc);

  int t = threadIdx.x, w = t >> 6, lane = t & 63, lr = lane & 15, g = lane >> 4;
  int wr = w >> 1, wc = w & 1;
  if (gid < 2) {
    f16* out = (gid == 0) ? Qo : Ko;
#pragma unroll
    for (int mi = 0; mi < 4; mi++) {
      int m0 = bm + wr * 64 + mi * 16 + 4 * g;
      int b = m0 >> 11, i0 = m0 & 2047;
#pragma unroll
      for (int ni = 0; ni < 4; ni++) {
        int n = bn + wc * 64 + ni * 16 + lr;
        int h = n >> 6, d = n & 63;
        size_t base = (((size_t)(b * NH + h)) * TT + i0) * DH + d;
#pragma unroll
        for (int r = 0; r < 4; r++)
          out[base + (size_t)r * DH] = (f16)acc[mi][ni][r];
      }
    }
  } else {
#pragma unroll
    for (int mi = 0; mi < 4; mi++) {
      int m0 = bm + wr * 64 + mi * 16 + 4 * g;
      int b = m0 >> 11, j0 = m0 & 2047;
#pragma unroll
      for (int ni = 0; ni < 4; ni++) {
        int n = bn + wc * 64 + ni * 16 + lr;
        int h = n >> 6, d = n & 63;
        f16x4 pk = { (f16)acc[mi][ni][0], (f16)acc[mi][ni][1],
                     (f16)acc[mi][ni][2], (f16)acc[mi][ni][3] };
        *reinterpret_cast<f16x4*>(&Vt[(((size_t)(b * NH + h)) * DH + d) * TT + j0]) = pk;
      }
    }
  }
}

// ---------------- output projection (XCD-chunked: 32 contiguous tiles/XCD) ----------------
__global__ __launch_bounds__(256) void out_gemm(const f16* __restrict__ Ob, const f16* __restrict__ wo,
                                                const float* __restrict__ bo, float* __restrict__ Y) {
  __shared__ f16 As[2][4096];
  __shared__ f16 Bs[2][4096];
  int o = blockIdx.x;
  int bid = (o & 7) * 32 + (o >> 3);
  int bm = (bid >> 3) * 128, bn = (bid & 7) * 128;
  f32x4 acc[4][4] = {};
  gemm_mainloop(Ob, wo, bm, bn, As, Bs, acc);
  int t = threadIdx.x, w = t >> 6, lane = t & 63, lr = lane & 15, g = lane >> 4;
  int wr = w >> 1, wc = w & 1;
#pragma unroll
  for (int mi = 0; mi < 4; mi++) {
    int m0 = bm + wr * 64 + mi * 16 + 4 * g;
#pragma unroll
    for (int ni = 0; ni < 4; ni++) {
      int n = bn + wc * 64 + ni * 16 + lr;
      float bias = bo[n];
#pragma unroll
      for (int r = 0; r < 4; r++)
        Y[(size_t)(m0 + r) * DM + n] = acc[mi][ni][r] + bias;
    }
  }
}

// ---------------- flash attention: R10/R12 exact (4-wave, reg-staged, raw barriers) ----------------
struct FB4 { f16x8 a, b, c, d; };

__global__ __launch_bounds__(256, 2) void attn_kernel(const f16* __restrict__ Q, const f16* __restrict__ K,
                                                      const f16* __restrict__ V, const f16* __restrict__ FBf,
                                                      f16* __restrict__ O) {
  __shared__ f16 KV[2][8192];   // 16KB per buf: K @0, V^T @+8KB
  int o = blockIdx.x;
  int xcd = o & 7, idx = o >> 3;            // XCD-aware: 4 bh per XCD
  int bh = 4 * xcd + (idx >> 4), qblk = idx & 15;
  int h = bh & 15, b = bh >> 4;
  int tt = threadIdx.x, w = tt >> 6, lane = tt & 63;
  int col = lane & 31, hi = lane >> 5;
  int qi = qblk * 128 + w * 32 + col;

  const f16* qp = Q + ((size_t)bh * TT + qi) * DH + hi * 8;
  f16x8 qf[4];
#pragma unroll
  for (int s = 0; s < 4; s++) qf[s] = *reinterpret_cast<const f16x8*>(qp + 16 * s);

  const float nc2 = -exp2f(-(float)(h + 1)) * LOG2E;
  int qtp = qblk * 4 + w;
  const f16x8* fbp = reinterpret_cast<const f16x8*>(FBf) + ((size_t)qtp << 13) + (lane << 1);

  f32x4 rsv = { 0.f, 0.f, 0.f, 0.f };
  f32x16 oacc0 = {}, oacc1 = {};

  int rho0 = tt >> 3, G = tt & 7;
  int f0 = (rho0 & 7) ^ (3 * ((rho0 >> 4) & 1));
  int J0 = (rho0 & 19) | ((rho0 & 4) << 1) | ((rho0 & 8) >> 1);   // swap bits 2<->3
  const f16* kp0 = K + ((size_t)bh * TT + J0) * DH + (G ^ f0) * 8;
  const f16* kp1 = K + ((size_t)bh * TT + 32 + J0) * DH + (G ^ f0) * 8;
  const f16* vp0 = V + ((size_t)bh * DH + rho0) * TT + (G ^ f0) * 8;
  const f16* vp1 = V + ((size_t)bh * DH + 32 + rho0) * TT + (G ^ f0) * 8;

  f16x8 r0, r1, r2, r3;
  auto LOADR = [&](int kv0) {
    r0 = *reinterpret_cast<const f16x8*>(kp0 + (size_t)kv0 * DH);
    r1 = *reinterpret_cast<const f16x8*>(kp1 + (size_t)kv0 * DH);
    r2 = *reinterpret_cast<const f16x8*>(vp0 + kv0);
    r3 = *reinterpret_cast<const f16x8*>(vp1 + kv0);
  };
  auto WRITE = [&](int bufi) {
    char* base = (char*)KV[bufi];
    *reinterpret_cast<f16x8*>(base + tt * 16) = r0;
    *reinterpret_cast<f16x8*>(base + 4096 + tt * 16) = r1;
    *reinterpret_cast<f16x8*>(base + 8192 + tt * 16) = r2;
    *reinterpret_cast<f16x8*>(base + 12288 + tt * 16) = r3;
  };

  int fcol = (col & 7) ^ (3 * ((col >> 4) & 1));
  int kb0 = col * 128;
  int ksw[4];
#pragma unroll
  for (int s = 0; s < 4; s++) ksw[s] = ((2 * s + hi) ^ fcol) << 4;

  auto FBLOAD = [&](int t) {
    FB4 f;
    f.a = fbp[256 * t];
    f.b = fbp[256 * t + 1];
    f.c = fbp[256 * t + 128];
    f.d = fbp[256 * t + 129];
    return f;
  };

  auto CMP = [&](int bufi, const FB4& fb) {
    const char* Kb = (const char*)KV[bufi];
    f32x16 S0 = {}, S1 = {};
    __builtin_amdgcn_s_setprio(1);
#pragma unroll
    for (int s = 0; s < 4; s++) {
      f16x8 ka0 = *reinterpret_cast<const f16x8*>(Kb + kb0 + ksw[s]);
      f16x8 ka1 = *reinterpret_cast<const f16x8*>(Kb + 4096 + kb0 + ksw[s]);
      S0 = __builtin_amdgcn_mfma_f32_32x32x16_f16(ka0, qf[s], S0, 0, 0, 0);
      S1 = __builtin_amdgcn_mfma_f32_32x32x16_f16(ka1, qf[s], S1, 0, 0, 0);
    }
    __builtin_amdgcn_s_setprio(0);
    float p0[16], p1[16];
#pragma unroll
    for (int r = 0; r < 16; r++) {
      float fb0 = (float)((r < 8) ? fb.a[r] : fb.b[r - 8]);
      float fb1 = (float)((r < 8) ? fb.c[r] : fb.d[r - 8]);
      p0[r] = __builtin_amdgcn_exp2f(fmaf(fb0, nc2, S0[r]));
      p1[r] = __builtin_amdgcn_exp2f(fmaf(fb1, nc2, S1[r]));
    }
#pragma unroll
    for (int r = 0; r < 4; r++) {
      f32x4 pa = { p0[4 * r], p0[4 * r + 1], p0[4 * r + 2], p0[4 * r + 3] };
      f32x4 pc = { p1[4 * r], p1[4 * r + 1], p1[4 * r + 2], p1[4 * r + 3] };
      rsv += pa + pc;
    }
    f16x8 pb[4];
#pragma unroll
    for (int s2 = 0; s2 < 2; s2++) {
      union { f16x8 v; fp16x2 hh[4]; } u0, u1;
#pragma unroll
      for (int q2 = 0; q2 < 4; q2++) {
        u0.hh[q2] = __builtin_amdgcn_cvt_pkrtz(p0[8 * s2 + 2 * q2], p0[8 * s2 + 2 * q2 + 1]);
        u1.hh[q2] = __builtin_amdgcn_cvt_pkrtz(p1[8 * s2 + 2 * q2], p1[8 * s2 + 2 * q2 + 1]);
      }
      pb[s2] = u0.v; pb[2 + s2] = u1.v;
    }
    __builtin_amdgcn_s_setprio(1);
#pragma unroll
    for (int s2 = 0; s2 < 4; s2++) {
      f16x8 va0 = *reinterpret_cast<const f16x8*>(Kb + 8192 + kb0 + ksw[s2]);
      f16x8 va1 = *reinterpret_cast<const f16x8*>(Kb + 12288 + kb0 + ksw[s2]);
      oacc0 = __builtin_amdgcn_mfma_f32_32x32x16_f16(va0, pb[s2], oacc0, 0, 0, 0);
      oacc1 = __builtin_amdgcn_mfma_f32_32x32x16_f16(va1, pb[s2], oacc1, 0, 0, 0);
    }
    __builtin_amdgcn_s_setprio(0);
  };

  LOADR(0);
  WRITE(0);
  LOADR(64);
  FB4 fA = FBLOAD(0);
  FB4 fB = FBLOAD(1);
  LGKM0;
  __builtin_amdgcn_s_barrier();
  SB0;

#pragma unroll 1
  for (int tp = 0; tp < 16; tp++) {
    int t0 = 2 * tp;
    CMP(0, fA);
    WRITE(1);
    if (t0 + 2 < 32) { LOADR((t0 + 2) << 6); fA = FBLOAD(t0 + 2); }
    LGKM0;
    __builtin_amdgcn_s_barrier();
    SB0;
    CMP(1, fB);
    if (t0 + 2 < 32) {
      WRITE(0);
      if (t0 + 3 < 32) { LOADR((t0 + 3) << 6); fB = FBLOAD(t0 + 3); }
      LGKM0;
      __builtin_amdgcn_s_barrier();
      SB0;
    }
  }

  float lsum = (rsv[0] + rsv[1]) + (rsv[2] + rsv[3]);
  lsum += __shfl_xor(lsum, 32, 64);
  float inv = __builtin_amdgcn_rcpf(lsum);

  size_t ob = ((size_t)b * TT + qi) * DM + h * DH + 4 * hi;
  const f32x16* oa[2] = { &oacc0, &oacc1 };
#pragma unroll
  for (int db = 0; db < 2; db++)
#pragma unroll
    for (int a = 0; a < 4; a++) {
      f16x4 o4 = { (f16)((*oa[db])[4 * a] * inv),     (f16)((*oa[db])[4 * a + 1] * inv),
                   (f16)((*oa[db])[4 * a + 2] * inv), (f16)((*oa[db])[4 * a + 3] * inv) };
      *reinterpret_cast<f16x4*>(&O[ob + 32 * db + 8 * a]) = o4;
    }
}

extern "C" void kernel_launch(void* const* d_in, const int* in_sizes, int n_in,
                              void* d_out, int out_size, void* d_ws, size_t ws_size,
                              hipStream_t stream) {
  const float* x  = (const float*)d_in[0];
  const float* cx = (const float*)d_in[1];
  const float* Wq = (const float*)d_in[2];
  const float* Wk = (const float*)d_in[3];
  const float* Wv = (const float*)d_in[4];
  const float* Wo = (const float*)d_in[5];
  const float* bo = (const float*)d_in[6];
  float* Y = (float*)d_out;

  const size_t NTOK = (size_t)2 * TT;
  f16* p = (f16*)d_ws;
  f16* xb  = p; p += NTOK * DM;
  f16* cb  = p; p += NTOK * DM;
  f16* wqb = p; p += (size_t)DM * DM;
  f16* wkb = p; p += (size_t)DM * DM;
  f16* wvb = p; p += (size_t)DM * DM;
  f16* wob = p; p += (size_t)DM * DM;
  f16* Qb  = p; p += NTOK * DM;
  f16* Kb  = p; p += NTOK * DM;
  f16* Vtb = p; p += NTOK * DM;
  f16* Ob  = p; p += NTOK * DM;
  f16* FBt = p;   // 8MB fragment-order bias table

  cvt_all<<<2048, 256, 0, stream>>>(x, cx, Wq, Wk, Wv, Wo, xb, cb, wqb, wkb, wvb, wob, FBt);
  qkv_gemm<<<768, 256, 0, stream>>>(xb, cb, wqb, wkb, wvb, Qb, Kb, Vtb);
  attn_kernel<<<512, 256, 0, stream>>>(Qb, Kb, Vtb, FBt, Ob);
  out_gemm<<<256, 256, 0, stream>>>(Ob, wob, bo, Y);
}